// Round 2
// baseline (85.919 us; speedup 1.0000x reference)
//
#include <hip/hip_runtime.h>

// L[b] = -i*(H kron I - I kron H^T) + DECAY
// H real symmetric 4x4: H = Om*Hd - D1*N1 - D2*N2 + V*Nrr
//   off-diag: 0.5*Om iff (x^y)==1 or (x^y)==2; diag(H) = {0, -D2, -D1, -D1-D2+V}
// DECAY (batch-independent, REAL):
//   diag[r] = -0.5*g*((i>>1)+(i&1)+(j>>1)+(j&1)), i=r>>2, j=r&3
//   +g at (i<2 && j<2 && k==i+2 && l==j+2)   [c1 (x) c1]
//   +g at (i,j even && k==i+1 && l==j+1)     [c2 (x) c2]
//
// ROUND 1 LESSON: never write more than out_size floats — layout chosen from
// out_size/B at launch, every store bounds-checked against n4.
// ROUND 2 LESSON: __builtin_nontemporal_store needs a clang ext_vector_type,
// HIP's float4 (HIP_vector_type class) is rejected -> use native fx4.
//
// THIS ROUND: 2 float4 per thread (one wave == one batch), wave-uniform batch
// index via readfirstlane -> scalar param loads, nontemporal streaming stores.

#define GAMMA_F 11363.636363636364f   // 1 / 88e-6

typedef float fx4 __attribute__((ext_vector_type(4)));  // native vector: NT-store OK

__device__ __forceinline__ float Hxy(int x, int y, float om2, float D1, float D2, float V) {
    if (x == y) {
        float d = 0.0f;
        if (x & 2) d -= D1;
        if (x & 1) d -= D2;
        if (x == 3) d += V;
        return d;
    }
    int t = x ^ y;
    return (t == 1 || t == 2) ? om2 : 0.0f;
}

__device__ __forceinline__ float decay_rc(int r, int c) {
    int i = r >> 2, j = r & 3, k = c >> 2, l = c & 3;
    float d = 0.0f;
    if (r == c)
        d = -0.5f * GAMMA_F * (float)((i >> 1) + (i & 1) + (j >> 1) + (j & 1));
    if (i < 2 && j < 2 && k == i + 2 && l == j + 2) d += GAMMA_F;      // c1 (x) c1
    if (!(i & 1) && !(j & 1) && k == i + 1 && l == j + 1) d += GAMMA_F; // c2 (x) c2
    return d;
}

// One fx4 = 2 adjacent complex elements of row r (cols c0, c0+1), e in [0,128).
__device__ __forceinline__ fx4 elem_pair(int e, float om2, float D1, float D2, float V) {
    int r  = e >> 3;
    int c0 = (e & 7) << 1;
    int i = r >> 2, j = r & 3;
    fx4 o;
    {
        int c = c0, k = c >> 2, l = c & 3;
        float im = 0.0f;
        if (j == l) im -= Hxy(i, k, om2, D1, D2, V);
        if (i == k) im += Hxy(j, l, om2, D1, D2, V);
        o.x = decay_rc(r, c);
        o.y = im;
    }
    {
        int c = c0 + 1, k = c >> 2, l = c & 3;
        float im = 0.0f;
        if (j == l) im -= Hxy(i, k, om2, D1, D2, V);
        if (i == k) im += Hxy(j, l, om2, D1, D2, V);
        o.z = decay_rc(r, c);
        o.w = im;
    }
    return o;
}

// Layout A: interleaved (re,im) float32; 128 float4/batch.
// 64 threads (= exactly one wave) per batch; each thread writes elements
// e0 and e0+64 -> both store instructions are 1 KiB dense per wave.
__global__ __launch_bounds__(256) void lindblad_cplx(
        const float* __restrict__ Om, const float* __restrict__ De,
        const float* __restrict__ dd1, const float* __restrict__ dd2,
        const float* __restrict__ dph, const float* __restrict__ Vv,
        fx4* __restrict__ out, int nthreads, int n4) {
    int g = blockIdx.x * blockDim.x + threadIdx.x;
    if (g >= nthreads) return;

    // g>>6 is identical for all 64 lanes of a wave (blocks are 256 = 4 waves,
    // wave-aligned) -> readfirstlane makes it provably uniform so the 6
    // parameter loads become scalar (s_load) instead of 64-lane broadcasts.
    int b = __builtin_amdgcn_readfirstlane(g >> 6);

    float om2 = 0.5f * Om[b];
    float bd  = De[b] + dph[b];
    float D1  = bd + dd1[b];
    float D2  = bd + dd2[b];
    float V   = Vv[b];

    int e0   = g & 63;
    int idx0 = (b << 7) + e0;   // float4 index of element e0
    int idx1 = idx0 + 64;       // element e0+64

    fx4 o0 = elem_pair(e0,      om2, D1, D2, V);
    fx4 o1 = elem_pair(e0 + 64, om2, D1, D2, V);

    // Pure streaming output (134 MB >> L2): nontemporal, don't allocate in L2.
    if (idx0 < n4) __builtin_nontemporal_store(o0, &out[idx0]);
    if (idx1 < n4) __builtin_nontemporal_store(o1, &out[idx1]);
}

// Layout B: out_size == B*256 -> one float32 per complex element (real part
// only = batch-independent DECAY). 64 float4 per batch row-major.
__global__ __launch_bounds__(256) void lindblad_real(
        fx4* __restrict__ out, int n4) {
    int g = blockIdx.x * blockDim.x + threadIdx.x;
    if (g >= n4) return;
    int e = g & 63;           // element within batch (float4 units)
    int r = e >> 2;           // row in 16x16
    int c0 = (e & 3) << 2;    // first of four cols
    fx4 o;
    o.x = decay_rc(r, c0 + 0);
    o.y = decay_rc(r, c0 + 1);
    o.z = decay_rc(r, c0 + 2);
    o.w = decay_rc(r, c0 + 3);
    __builtin_nontemporal_store(o, &out[g]);
}

extern "C" void kernel_launch(void* const* d_in, const int* in_sizes, int n_in,
                              void* d_out, int out_size, void* d_ws, size_t ws_size,
                              hipStream_t stream) {
    const float* Om  = (const float*)d_in[0];
    const float* De  = (const float*)d_in[1];
    const float* dd1 = (const float*)d_in[2];
    const float* dd2 = (const float*)d_in[3];
    const float* dph = (const float*)d_in[4];
    const float* dVv = (const float*)d_in[5];
    int B = in_sizes[0];

    const int block = 256;

    if (out_size == B * 256) {
        // real-only layout: exactly out_size floats = out_size/4 float4s
        int n4 = out_size >> 2;
        int grid = (n4 + block - 1) / block;
        lindblad_real<<<grid, block, 0, stream>>>((fx4*)d_out, n4);
    } else {
        // interleaved (re,im) layout, bounds-checked to never exceed out_size
        int n4 = out_size >> 2;               // total float4 capacity of d_out
        int want4 = B * 128;                  // what the full complex matrix needs
        if (n4 > want4) n4 = want4;
        int nthreads = B * 64;                // 2 float4 per thread
        int grid = (nthreads + block - 1) / block;
        lindblad_cplx<<<grid, block, 0, stream>>>(Om, De, dd1, dd2, dph, dVv,
                                                  (fx4*)d_out, nthreads, n4);
    }
}

// Round 3
// 85.119 us; speedup vs baseline: 1.0094x; 1.0094x over previous
//
#include <hip/hip_runtime.h>

// L[b] = -i*(H kron I - I kron H^T) + DECAY
// H real symmetric 4x4: H = Om*Hd - D1*N1 - D2*N2 + V*Nrr
//   off-diag: 0.5*Om iff (x^y)==1 or (x^y)==2; diag(H) = {0, -D2, -D1, -D1-D2+V}
// DECAY (batch-independent, REAL):
//   diag[r] = -0.5*g*((i>>1)+(i&1)+(j>>1)+(j&1)), i=r>>2, j=r&3
//   +g at (i<2 && j<2 && k==i+2 && l==j+2)   [c1 (x) c1]
//   +g at (i,j even && k==i+1 && l==j+1)     [c2 (x) c2]
//
// ROUND 1 LESSON: never write more than out_size floats.
// ROUND 2 LESSON: __builtin_nontemporal_store needs clang ext_vector_type.
// ROUND 3 LESSON: 65K short-lived waves (setup -> 2 stores -> die) stream at
//   only ~3.5 TB/s; NT stores / scalar loads / 2x-per-thread were all no-ops.
//   The 6 TB/s fill is a persistent looping grid -> emulate that shape.
//
// THIS ROUND: persistent grid-stride waves (8192 waves = 32/CU, one batch per
// wave per iteration), all lane-dependent selection hoisted out of the loop as
// ±1/0 float coefficients. Loop body: 4 s_loads, ~45 VALU, 2 NT dwordx4 stores.
// im rounding order matches the previous passing kernel exactly.

#define GAMMA_F 11363.636363636364f   // 1 / 88e-6

typedef float fx4 __attribute__((ext_vector_type(4)));

__device__ __forceinline__ float decay_rc(int r, int c) {
    int i = r >> 2, j = r & 3, k = c >> 2, l = c & 3;
    float d = 0.0f;
    if (r == c)
        d = -0.5f * GAMMA_F * (float)((i >> 1) + (i & 1) + (j >> 1) + (j & 1));
    if (i < 2 && j < 2 && k == i + 2 && l == j + 2) d += GAMMA_F;      // c1 (x) c1
    if (!(i & 1) && !(j & 1) && k == i + 1 && l == j + 1) d += GAMMA_F; // c2 (x) c2
    return d;
}

// im(r,c) = A + B,  A = -(j==l)*H[i][k],  B = +(i==k)*H[j][l]
// H[x][x] = cd1(x)*D1 + cd2(x)*D2 + cv(x)*V  with cd1=-(x>>1&1), cd2=-(x&1), cv=(x==3)
// H[x][y] = om2 iff (x^y) in {1,2}
__device__ __forceinline__ void im_coefs(int r, int c,
        float& fAh, float& fAom, float& fBh, float& fBom) {
    int i = r >> 2, j = r & 3, k = c >> 2, l = c & 3;
    bool jl = (j == l), ik = (i == k);
    int xik = i ^ k, xjl = j ^ l;
    bool oik = (xik == 1) || (xik == 2);
    bool ojl = (xjl == 1) || (xjl == 2);
    fAh  = (jl && ik)          ? -1.0f : 0.0f;   // -h[i] on diagonal
    fAom = (jl && !ik && oik)  ? -1.0f : 0.0f;   // -om2 off-diagonal (col block)
    fBh  = (ik && jl)          ?  1.0f : 0.0f;   // +h[j] on diagonal
    fBom = (ik && !jl && ojl)  ?  1.0f : 0.0f;   // +om2 off-diagonal (row block)
}

__device__ __forceinline__ void h_coefs(int x, float& cd1, float& cd2, float& cv) {
    cd1 = (x & 2) ? -1.0f : 0.0f;
    cd2 = (x & 1) ? -1.0f : 0.0f;
    cv  = (x == 3) ? 1.0f : 0.0f;
}

// Layout A: interleaved (re,im) f32, 128 float4/batch. Persistent waves:
// one wave == one batch per loop iteration; lane t handles float4 elements
// t (row r0=t>>3) and t+64 (row r0+8), cols 2*(t&7), 2*(t&7)+1.
__global__ __launch_bounds__(256) void lindblad_cplx(
        const float* __restrict__ Om, const float* __restrict__ De,
        const float* __restrict__ dd1, const float* __restrict__ dd2,
        const float* __restrict__ dph, const float* __restrict__ Vv,
        fx4* __restrict__ out, int B, int n4, int nwaves) {
    const int lane = threadIdx.x & 63;
    const int wid  = __builtin_amdgcn_readfirstlane(
        blockIdx.x * (blockDim.x >> 6) + (threadIdx.x >> 6));

    // ---- loop-invariant per-thread geometry & coefficients ----
    const int r0 = lane >> 3;
    const int c0 = (lane & 7) << 1;
    const int r1 = r0 + 8;
    const int i0 = r0 >> 2, j0 = r0 & 3;
    const int i1 = r1 >> 2, j1 = r1 & 3;

    const float re00 = decay_rc(r0, c0), re01 = decay_rc(r0, c0 + 1);
    const float re10 = decay_rc(r1, c0), re11 = decay_rc(r1, c0 + 1);

    float a00h, a00o, b00h, b00o;  im_coefs(r0, c0,     a00h, a00o, b00h, b00o);
    float a01h, a01o, b01h, b01o;  im_coefs(r0, c0 + 1, a01h, a01o, b01h, b01o);
    float a10h, a10o, b10h, b10o;  im_coefs(r1, c0,     a10h, a10o, b10h, b10o);
    float a11h, a11o, b11h, b11o;  im_coefs(r1, c0 + 1, a11h, a11o, b11h, b11o);

    float ci0_1, ci0_2, ci0_v;  h_coefs(i0, ci0_1, ci0_2, ci0_v);
    float cj0_1, cj0_2, cj0_v;  h_coefs(j0, cj0_1, cj0_2, cj0_v);
    float ci1_1, ci1_2, ci1_v;  h_coefs(i1, ci1_1, ci1_2, ci1_v);
    float cj1_1, cj1_2, cj1_v;  h_coefs(j1, cj1_1, cj1_2, cj1_v);

    // ---- steady-state store stream ----
    for (int b = wid; b < B; b += nwaves) {
        float om2 = 0.5f * Om[b];           // b wave-uniform -> scalar loads
        float bd  = De[b] + dph[b];
        float D1  = bd + dd1[b];
        float D2  = bd + dd2[b];
        float V   = Vv[b];

        // diagonal H values needed by this thread's two rows
        float hi0 = fmaf(ci0_v, V, fmaf(ci0_2, D2, ci0_1 * D1));
        float hj0 = fmaf(cj0_v, V, fmaf(cj0_2, D2, cj0_1 * D1));
        float hi1 = fmaf(ci1_v, V, fmaf(ci1_2, D2, ci1_1 * D1));
        float hj1 = fmaf(cj1_v, V, fmaf(cj1_2, D2, cj1_1 * D1));

        float im00 = fmaf(a00h, hi0, a00o * om2) + fmaf(b00h, hj0, b00o * om2);
        float im01 = fmaf(a01h, hi0, a01o * om2) + fmaf(b01h, hj0, b01o * om2);
        float im10 = fmaf(a10h, hi1, a10o * om2) + fmaf(b10h, hj1, b10o * om2);
        float im11 = fmaf(a11h, hi1, a11o * om2) + fmaf(b11h, hj1, b11o * om2);

        fx4 o0 = {re00, im00, re01, im01};
        fx4 o1 = {re10, im10, re11, im11};

        int idx0 = (b << 7) + lane;
        int idx1 = idx0 + 64;
        if (idx0 < n4) __builtin_nontemporal_store(o0, &out[idx0]);
        if (idx1 < n4) __builtin_nontemporal_store(o1, &out[idx1]);
    }
}

// Layout B: out_size == B*256 -> one f32 per complex element (real part only =
// batch-independent DECAY). 64 float4 per batch row-major.
__global__ __launch_bounds__(256) void lindblad_real(
        fx4* __restrict__ out, int n4) {
    int g = blockIdx.x * blockDim.x + threadIdx.x;
    if (g >= n4) return;
    int e = g & 63;
    int r = e >> 2;
    int c0 = (e & 3) << 2;
    fx4 o;
    o.x = decay_rc(r, c0 + 0);
    o.y = decay_rc(r, c0 + 1);
    o.z = decay_rc(r, c0 + 2);
    o.w = decay_rc(r, c0 + 3);
    __builtin_nontemporal_store(o, &out[g]);
}

extern "C" void kernel_launch(void* const* d_in, const int* in_sizes, int n_in,
                              void* d_out, int out_size, void* d_ws, size_t ws_size,
                              hipStream_t stream) {
    const float* Om  = (const float*)d_in[0];
    const float* De  = (const float*)d_in[1];
    const float* dd1 = (const float*)d_in[2];
    const float* dd2 = (const float*)d_in[3];
    const float* dph = (const float*)d_in[4];
    const float* dVv = (const float*)d_in[5];
    int B = in_sizes[0];

    const int block = 256;

    if (out_size == B * 256) {
        int n4 = out_size >> 2;
        int grid = (n4 + block - 1) / block;
        lindblad_real<<<grid, block, 0, stream>>>((fx4*)d_out, n4);
    } else {
        int n4 = out_size >> 2;               // float4 capacity of d_out
        int want4 = B * 128;
        if (n4 > want4) n4 = want4;
        // persistent grid: 2048 blocks x 4 waves = 8192 waves = 32 waves/CU
        int nblocks = (B + 3) / 4;            // never launch fully-idle blocks
        if (nblocks > 2048) nblocks = 2048;
        int nwaves = nblocks * (block / 64);
        lindblad_cplx<<<nblocks, block, 0, stream>>>(Om, De, dd1, dd2, dph, dVv,
                                                     (fx4*)d_out, B, n4, nwaves);
    }
}